// Round 1
// baseline (1194.681 us; speedup 1.0000x reference)
//
#include <hip/hip_runtime.h>

// Problem constants (from reference): N=8192 nodes, E=16384 edges, D=4.
#define NN 8192
#define EE 16384
#define NCHUNK 64              // split-N factor for column-sum pass
#define ROWS_PER_CHUNK (NN / NCHUNK)   // 128

// Workspace layout (floats):
//   u  : [0, NN)
//   v  : [NN, 2*NN)
//   w  : [2*NN, 3*NN)
//   pa : [3*NN, 3*NN + NCHUNK*EE)            partial col-sums of Ro*u
//   pb : [... , +NCHUNK*EE)                   partial col-sums of Ri*v
//   so : [... , +EE)
//   si : [... , +EE)
// Total ~8.6 MB.

__global__ __launch_bounds__(256) void prep_kernel(
    const float* __restrict__ X, const float* __restrict__ kern,
    float* __restrict__ u, float* __restrict__ v, float* __restrict__ w) {
    int n = blockIdx.x * 256 + threadIdx.x;
    if (n >= NN) return;
    float4 x = *(const float4*)(X + (size_t)n * 4);
    float k0 = kern[0], k1 = kern[1], k2 = kern[2],  k3 = kern[3];
    float k4 = kern[4], k5 = kern[5], k6 = kern[6],  k7 = kern[7];
    float k8 = kern[8], k9 = kern[9], k10 = kern[10], k11 = kern[11];
    u[n] = x.x * k0 + x.y * k1 + x.z * k2 + x.w * k3;
    v[n] = x.x * k4 + x.y * k5 + x.z * k6 + x.w * k7;
    w[n] = x.x * k8 + x.y * k9 + x.z * k10 + x.w * k11;
}

// Pass 1: partial column sums. grid = (EE/1024, NCHUNK), block = 256.
// Thread t of tile handles 4 consecutive e-values (float4 coalesced);
// loops over its 128-row chunk. Writes partials — no atomics.
__global__ __launch_bounds__(256) void colsum_kernel(
    const float* __restrict__ Ri, const float* __restrict__ Ro,
    const float* __restrict__ u, const float* __restrict__ v,
    float* __restrict__ pa, float* __restrict__ pb) {
    const int e0 = blockIdx.x * 1024 + threadIdx.x * 4;
    const int chunk = blockIdx.y;
    const int nbeg = chunk * ROWS_PER_CHUNK;
    float4 aa = make_float4(0.f, 0.f, 0.f, 0.f);
    float4 bb = make_float4(0.f, 0.f, 0.f, 0.f);
#pragma unroll 4
    for (int i = 0; i < ROWS_PER_CHUNK; ++i) {
        const int n = nbeg + i;
        const float un = u[n];   // wave-uniform -> scalar load
        const float vn = v[n];
        const float4 ro = *(const float4*)(Ro + (size_t)n * EE + e0);
        const float4 ri = *(const float4*)(Ri + (size_t)n * EE + e0);
        aa.x += ro.x * un; aa.y += ro.y * un; aa.z += ro.z * un; aa.w += ro.w * un;
        bb.x += ri.x * vn; bb.y += ri.y * vn; bb.z += ri.z * vn; bb.w += ri.w * vn;
    }
    *(float4*)(pa + (size_t)chunk * EE + e0) = aa;
    *(float4*)(pb + (size_t)chunk * EE + e0) = bb;
}

// Reduce partials across chunks and fold in per-edge weight e[].
__global__ __launch_bounds__(256) void edge_scale_kernel(
    const float* __restrict__ ew,
    const float* __restrict__ pa, const float* __restrict__ pb,
    float* __restrict__ so, float* __restrict__ si) {
    int e = blockIdx.x * 256 + threadIdx.x;
    if (e >= EE) return;
    float sa = 0.f, sb = 0.f;
#pragma unroll 8
    for (int c = 0; c < NCHUNK; ++c) {
        sa += pa[(size_t)c * EE + e];
        sb += pb[(size_t)c * EE + e];
    }
    float we = ew[e];
    so[e] = we * sa;
    si[e] = we * sb;
}

// Pass 2: one block per output row n. out[n] = Ri[n,:]·so + Ro[n,:]·si + w[n].
__global__ __launch_bounds__(256) void rowdot_kernel(
    const float* __restrict__ Ri, const float* __restrict__ Ro,
    const float* __restrict__ so, const float* __restrict__ si,
    const float* __restrict__ w, float* __restrict__ out) {
    const int n = blockIdx.x;
    const float4* ri4 = (const float4*)(Ri + (size_t)n * EE);
    const float4* ro4 = (const float4*)(Ro + (size_t)n * EE);
    const float4* so4 = (const float4*)so;
    const float4* si4 = (const float4*)si;
    float acc = 0.f;
#pragma unroll 4
    for (int i = threadIdx.x; i < EE / 4; i += 256) {
        float4 a = ri4[i], s1 = so4[i];
        float4 b = ro4[i], s2 = si4[i];
        acc += a.x * s1.x + a.y * s1.y + a.z * s1.z + a.w * s1.w;
        acc += b.x * s2.x + b.y * s2.y + b.z * s2.z + b.w * s2.w;
    }
    // wave-64 shuffle reduce
#pragma unroll
    for (int off = 32; off > 0; off >>= 1) acc += __shfl_down(acc, off, 64);
    __shared__ float sred[4];
    if ((threadIdx.x & 63) == 0) sred[threadIdx.x >> 6] = acc;
    __syncthreads();
    if (threadIdx.x == 0) {
        out[n] = sred[0] + sred[1] + sred[2] + sred[3] + w[n];
    }
}

extern "C" void kernel_launch(void* const* d_in, const int* in_sizes, int n_in,
                              void* d_out, int out_size, void* d_ws, size_t ws_size,
                              hipStream_t stream) {
    const float* X    = (const float*)d_in[0];   // [N,4]
    const float* ew   = (const float*)d_in[1];   // [E,1]
    const float* Ri   = (const float*)d_in[2];   // [N,E]
    const float* Ro   = (const float*)d_in[3];   // [N,E]
    const float* kern = (const float*)d_in[4];   // [12,1]
    float* out = (float*)d_out;                  // [N,1]

    float* ws = (float*)d_ws;
    float* u  = ws;
    float* v  = u + NN;
    float* w  = v + NN;
    float* pa = w + NN;
    float* pb = pa + (size_t)NCHUNK * EE;
    float* so = pb + (size_t)NCHUNK * EE;
    float* si = so + EE;

    prep_kernel<<<NN / 256, 256, 0, stream>>>(X, kern, u, v, w);
    colsum_kernel<<<dim3(EE / 1024, NCHUNK), 256, 0, stream>>>(Ri, Ro, u, v, pa, pb);
    edge_scale_kernel<<<EE / 256, 256, 0, stream>>>(ew, pa, pb, so, si);
    rowdot_kernel<<<NN, 256, 0, stream>>>(Ri, Ro, so, si, w, out);
}